// Round 10
// baseline (49.205 us; speedup 1.0000x reference)
//
#include <hip/hip_runtime.h>
#include <hip/hip_bf16.h>

// DeViSE bf16-MFMA. Round 10: R9 + (1) bn-major XCD-chunked block swizzle for
// the fused GEMM (each XCD's 64-block chunk touches only 2 B-panels = 1MB,
// fits per-XCD L2), (2) short S-blocks first (no tail), (3) s_setprio around
// the MFMA cluster (role-diverse waves at 2-3 blocks/CU).
//
// Workspace layout (bytes):
//   imgB  [2048][2048] bf16 @ 0
//   WcomB [2048][2048] bf16 @ 8,388,608   (rows 0-999 Wcls, 1000-1023 zero, 1024+ Wvis)
//   Vb    [2048][1024] bf16 @ 16,777,216
//   Sb    [1024][1024] bf16 @ 20,971,520
//   wordB [1024][320]  bf16 @ 23,068,672  (zero-pad rows>=1000, cols>=300)
//   WsemB [1024][320]  bf16 @ 23,724,032  (zero-pad cols>=300)

typedef __bf16 bf16x8 __attribute__((ext_vector_type(8)));
typedef float  f32x4  __attribute__((ext_vector_type(4)));

#define GLOAD_LDS16(gptr, lptr)                                                     \
  __builtin_amdgcn_global_load_lds((__attribute__((address_space(1))) void*)(gptr), \
                                   (__attribute__((address_space(3))) void*)(lptr), \
                                   16, 0, 0)

template <int N> __device__ __forceinline__ void wait_vmcnt() {
  if constexpr (N == 0)      asm volatile("s_waitcnt vmcnt(0)" ::: "memory");
  else if constexpr (N == 4) asm volatile("s_waitcnt vmcnt(4)" ::: "memory");
  else if constexpr (N == 6) asm volatile("s_waitcnt vmcnt(6)" ::: "memory");
  else static_assert(N == 0 || N == 4 || N == 6, "add vmcnt case");
}

// ---------------- merged convert kernel ----------------
__device__ __forceinline__ bf16x8 cvt8(const float* src) {
  const float4* s = (const float4*)src;
  float4 x = s[0], y = s[1];
  bf16x8 o;
  o[0] = (__bf16)x.x; o[1] = (__bf16)x.y; o[2] = (__bf16)x.z; o[3] = (__bf16)x.w;
  o[4] = (__bf16)y.x; o[5] = (__bf16)y.y; o[6] = (__bf16)y.z; o[7] = (__bf16)y.w;
  return o;
}

__global__ void cvt_all_k(const float* __restrict__ image, const float* __restrict__ Wcls,
                          const float* __restrict__ Wvis, const float* __restrict__ wemb,
                          const float* __restrict__ Wsem,
                          __bf16* __restrict__ imgB, __bf16* __restrict__ WcomB,
                          __bf16* __restrict__ wordB, __bf16* __restrict__ WsemB) {
  const int blk = blockIdx.x, tid = threadIdx.x;
  if (blk < 2048) {
    int i = blk * 256 + tid;
    ((bf16x8*)imgB)[i] = cvt8(image + (size_t)i * 8);
  } else if (blk < 4096) {
    int i = (blk - 2048) * 256 + tid;
    int row = i >> 8, cc = (i & 255) * 8;
    bf16x8 o;
    if (row < 1000)       o = cvt8(Wcls + (size_t)row * 2048 + cc);
    else if (row >= 1024) o = cvt8(Wvis + (size_t)(row - 1024) * 2048 + cc);
    else { for (int j = 0; j < 8; ++j) o[j] = (__bf16)0.f; }
    ((bf16x8*)WcomB)[i] = o;
  } else if (blk < 5376) {
    int i = (blk - 4096) * 256 + tid;
    int r = i / 320, c = i - r * 320;
    float v = (r < 1000 && c < 300) ? wemb[(size_t)r * 300 + c] : 0.f;
    wordB[i] = (__bf16)v;
  } else {
    int i = (blk - 5376) * 256 + tid;
    int r = i / 320, c = i - r * 320;
    float v = (c < 300) ? Wsem[(size_t)r * 300 + c] : 0.f;
    WsemB[i] = (__bf16)v;
  }
}

// ------- bf16 GEMM body, C = A @ B^T, BK=64, 3-buffer depth-2 counted pipeline -------
// LDS: At[3][BM*64] bf16 then Bt[3][BN*64] bf16 (16B chunk swizzle:
// logical chunk (r,c) of [rows][64]bf16 tile at slot r*8 + (c^(r&7));
// staging pre-swizzles the GLOBAL source, LDS dest stays linear).
// EPI 0: col<1000 -> outF=acc+bias1; col>=1024 -> outB=bf16(relu(acc+bias2)) at col-1024
// EPI 1: outB = bf16(relu(acc+bias1))
// EPI 2: col<1000 -> outF = acc
template <int WTM, int WTN, int NWM, int NWN, int EPI>
__device__ __forceinline__ void gemm_body(char* smem,
    const __bf16* __restrict__ A, const __bf16* __restrict__ Bm,
    const float* __restrict__ bias1, const float* __restrict__ bias2,
    float* __restrict__ outF, __bf16* __restrict__ outB, int K, int bm, int bn) {
  constexpr int BM = NWM * WTM, BN = NWN * WTN, NTHR = NWM * NWN * 64;
  constexpr int AM = WTM / 16, AN = WTN / 16;
  constexpr int LA = BM * 8 / NTHR, LB = BN * 8 / NTHR;   // 16B chunks per thread
  constexpr int LPS = LA + LB;
  char* AtB = smem;                        // 3 bufs x BM*128 bytes
  char* BtB = smem + 3 * BM * 128;         // 3 bufs x BN*128 bytes
  const int tid  = threadIdx.x;
  const int lane = tid & 63;
  const int wv   = tid >> 6;
  const int wvr  = wv / NWN, wvc = wv % NWN;

  f32x4 acc[AM][AN];
#pragma unroll
  for (int m = 0; m < AM; ++m)
#pragma unroll
    for (int n = 0; n < AN; ++n) acc[m][n] = (f32x4){0.f, 0.f, 0.f, 0.f};

  // kt-invariant swizzled read slots (bf16x8 index within a buffer)
  int slotA[2][AM], slotB[2][AN];
#pragma unroll
  for (int kh = 0; kh < 2; ++kh) {
#pragma unroll
    for (int m = 0; m < AM; ++m) {
      int r = wvr * WTM + m * 16 + (lane & 15);
      slotA[kh][m] = r * 8 + ((kh * 4 + (lane >> 4)) ^ (r & 7));
    }
#pragma unroll
    for (int n = 0; n < AN; ++n) {
      int r = wvc * WTN + n * 16 + (lane & 15);
      slotB[kh][n] = r * 8 + ((kh * 4 + (lane >> 4)) ^ (r & 7));
    }
  }

  const __bf16* Ab = A  + (size_t)(bm * BM) * K;
  const __bf16* Bb = Bm + (size_t)(bn * BN) * K;

#define STAGE64(buf, kt)                                                       \
  do {                                                                         \
    _Pragma("unroll")                                                          \
    for (int j = 0; j < LA; ++j) {                                             \
      int s = j * NTHR + tid;                                                  \
      int r = s >> 3, c = (s & 7) ^ (r & 7);                                   \
      GLOAD_LDS16(Ab + (size_t)r * K + (kt) * 64 + c * 8,                      \
                  AtB + (buf) * (BM * 128) + s * 16);                          \
    }                                                                          \
    _Pragma("unroll")                                                          \
    for (int j = 0; j < LB; ++j) {                                             \
      int s = j * NTHR + tid;                                                  \
      int r = s >> 3, c = (s & 7) ^ (r & 7);                                   \
      GLOAD_LDS16(Bb + (size_t)r * K + (kt) * 64 + c * 8,                      \
                  BtB + (buf) * (BN * 128) + s * 16);                          \
    }                                                                          \
  } while (0)

  const int nkt = K >> 6;      // >= 5 for all our shapes
  STAGE64(0, 0);
  STAGE64(1, 1);

  int cur = 0;
  for (int kt = 0; kt < nkt; ++kt) {
    // Outstanding: STAGE(kt) (+ STAGE(kt+1) if issued). Retire only STAGE(kt);
    // STAGE(kt+1)'s LPS loads keep flying across this barrier + compute phase.
    if (kt + 1 < nkt) wait_vmcnt<LPS>();
    else              wait_vmcnt<0>();
    __builtin_amdgcn_s_barrier();

    bf16x8 af[2][AM], bfr[2][AN];
    const bf16x8* Ap = (const bf16x8*)(AtB + cur * (BM * 128));
    const bf16x8* Bp = (const bf16x8*)(BtB + cur * (BN * 128));
#pragma unroll
    for (int kh = 0; kh < 2; ++kh) {
#pragma unroll
      for (int m = 0; m < AM; ++m) af[kh][m]  = Ap[slotA[kh][m]];
#pragma unroll
      for (int n = 0; n < AN; ++n) bfr[kh][n] = Bp[slotB[kh][n]];
    }
    __builtin_amdgcn_sched_barrier(0);   // ds_reads issued before STAGE

    if (kt + 2 < nkt) {
      int nb = cur + 2; if (nb >= 3) nb -= 3;
      STAGE64(nb, kt + 2);               // depth-2: flies across 2 phases
    }
    __builtin_amdgcn_sched_barrier(0);   // STAGE issued before MFMA cluster

    __builtin_amdgcn_s_setprio(1);       // T5: favor MFMA-entering wave
#pragma unroll
    for (int kh = 0; kh < 2; ++kh)
#pragma unroll
      for (int m = 0; m < AM; ++m)
#pragma unroll
        for (int n = 0; n < AN; ++n)
          acc[m][n] = __builtin_amdgcn_mfma_f32_16x16x32_bf16(af[kh][m], bfr[kh][n],
                                                              acc[m][n], 0, 0, 0);
    __builtin_amdgcn_s_setprio(0);
    ++cur; if (cur >= 3) cur = 0;
  }
#undef STAGE64

  // epilogue: C/D layout col=lane&15, row=(lane>>4)*4+j (m89/m91-verified)
#pragma unroll
  for (int m = 0; m < AM; ++m) {
    const int row0 = bm * BM + wvr * WTM + m * 16 + ((lane >> 4) << 2);
#pragma unroll
    for (int n = 0; n < AN; ++n) {
      const int col = bn * BN + wvc * WTN + n * 16 + (lane & 15);
      if (EPI == 0) {
        if (col < 1000) {
          const float bz = bias1[col];
#pragma unroll
          for (int j = 0; j < 4; ++j)
            outF[(size_t)(row0 + j) * 1000 + col] = acc[m][n][j] + bz;
        } else if (col >= 1024) {
          const float bz = bias2[col - 1024];
#pragma unroll
          for (int j = 0; j < 4; ++j) {
            float v = acc[m][n][j] + bz;
            outB[(size_t)(row0 + j) * 1024 + (col - 1024)] = (__bf16)fmaxf(v, 0.f);
          }
        }
      } else if (EPI == 1) {
        const float bz = bias1[col];
#pragma unroll
        for (int j = 0; j < 4; ++j) {
          float v = acc[m][n][j] + bz;
          outB[(size_t)(row0 + j) * 1024 + col] = (__bf16)fmaxf(v, 0.f);
        }
      } else {
        if (col < 1000) {
#pragma unroll
          for (int j = 0; j < 4; ++j)
            outF[(size_t)(row0 + j) * 1000 + col] = acc[m][n][j];
        }
      }
    }
  }
}

// Blocks 0-255: S GEMM (64x64 tiles, waves 32x32) — short blocks lead, no tail.
// Blocks 256-767: fused logits+V GEMM (64x128 tiles, waves 32x64),
//   bn-major + XCD-chunked swizzle: each XCD's 64-block chunk = 2 bn x 32 bm
//   -> per-XCD B-slice 1MB (fits 4MB L2), A streams.
__global__ void __launch_bounds__(256, 2)
gemm_merged_k(const __bf16* __restrict__ imgB, const __bf16* __restrict__ WcomB,
              const __bf16* __restrict__ wordB, const __bf16* __restrict__ WsemB,
              const float* __restrict__ bcls, const float* __restrict__ bvis,
              const float* __restrict__ bsem,
              float* __restrict__ logits, __bf16* __restrict__ Vb,
              __bf16* __restrict__ Sb) {
  extern __shared__ char smem[];
  const int blk = blockIdx.x;
  if (blk < 256) {
    gemm_body<32, 32, 2, 2, 1>(smem, wordB, WsemB, bsem, nullptr, nullptr, Sb, 320,
                               blk >> 4, blk & 15);
  } else {
    const int l = blk - 256;                 // 0..511, 512 % 8 == 0 -> bijective
    const int s = (l & 7) * 64 + (l >> 3);   // XCD-chunked
    const int bn = s >> 5, bm = s & 31;      // bn-major: 16 bn x 32 bm
    gemm_body<32, 64, 2, 2, 0>(smem, imgB, WcomB, bcls, bvis, logits, Vb, 2048,
                               bm, bn);
  }
}

// scores: 64x64 blocks (waves 32x32), grid 16x32 = 512 blocks.
__global__ void __launch_bounds__(256, 2)
gemm_scores_k(const __bf16* __restrict__ Vb, const __bf16* __restrict__ Sb,
              float* __restrict__ scores) {
  extern __shared__ char smem[];
  gemm_body<32, 32, 2, 2, 2>(smem, Vb, Sb, nullptr, nullptr, scores, nullptr, 1024,
                             blockIdx.y, blockIdx.x);
}

// ---------------- launch ----------------

extern "C" void kernel_launch(void* const* d_in, const int* in_sizes, int n_in,
                              void* d_out, int out_size, void* d_ws, size_t ws_size,
                              hipStream_t stream) {
  const float* image = (const float*)d_in[0];
  const float* wemb  = (const float*)d_in[1];
  const float* Wcls  = (const float*)d_in[2];
  const float* bcls  = (const float*)d_in[3];
  const float* Wvis  = (const float*)d_in[4];
  const float* bvis  = (const float*)d_in[5];
  const float* Wsem  = (const float*)d_in[6];
  const float* bsem  = (const float*)d_in[7];

  float* logits = (float*)d_out;                  // [2048][1000]
  float* scores = logits + (size_t)2048 * 1000;   // [2048][1000]

  char* ws = (char*)d_ws;
  __bf16* imgB  = (__bf16*)(ws);
  __bf16* WcomB = (__bf16*)(ws + 8388608);
  __bf16* Vb    = (__bf16*)(ws + 16777216);
  __bf16* Sb    = (__bf16*)(ws + 20971520);
  __bf16* wordB = (__bf16*)(ws + 23068672);
  __bf16* WsemB = (__bf16*)(ws + 23724032);

  cvt_all_k<<<6656, 256, 0, stream>>>(image, Wcls, Wvis, wemb, Wsem,
                                      imgB, WcomB, wordB, WsemB);

  // S (256 blocks, 64x64, K=320) + fused (512 blocks, 64x128, K=2048)
  // dynamic LDS = 3*(64+128)*128 = 73728 B -> 2 blocks/CU
  gemm_merged_k<<<768, 256, 73728, stream>>>(imgB, WcomB, wordB, WsemB,
                                             bcls, bvis, bsem, logits, Vb, Sb);

  // scores: [2048 x 1024pad] = Vb @ Sb^T, K=1024, 64x64 tiles, grid (16,32)
  // dynamic LDS = 3*(64+64)*128 = 49152 B -> 3 blocks/CU
  gemm_scores_k<<<dim3(16, 32), 256, 49152, stream>>>(Vb, Sb, scores);
}

// Round 11
// 47.102 us; speedup vs baseline: 1.0446x; 1.0446x over previous
//
#include <hip/hip_runtime.h>
#include <hip/hip_bf16.h>

// DeViSE bf16-MFMA. Round 11: R9 base (best known: depth-2 counted vmcnt,
// 3 LDS buffers, no setprio/XCD-swizzle) with ONE change: fused GEMM block
// tile 128x128 via 512-thread 8-wave blocks (wave tile stays 32x64).
// B-panel staging re-reads halve: 402MB -> 268MB through L2/L3.
//   fused : 128x128 block (8 waves 32x64), BK=64, 3 bufs (96KB LDS), 256 blocks
//   S     : 64x128 block (8 waves 32x32), 128 blocks appended (tail-fill)
//   scores: 64x64 block (4 waves 32x32), 256-thr, grid (16,32)  [R9 exact]
//
// Workspace layout (bytes):
//   imgB  [2048][2048] bf16 @ 0
//   WcomB [2048][2048] bf16 @ 8,388,608   (rows 0-999 Wcls, 1000-1023 zero, 1024+ Wvis)
//   Vb    [2048][1024] bf16 @ 16,777,216
//   Sb    [1024][1024] bf16 @ 20,971,520
//   wordB [1024][320]  bf16 @ 23,068,672  (zero-pad rows>=1000, cols>=300)
//   WsemB [1024][320]  bf16 @ 23,724,032  (zero-pad cols>=300)

typedef __bf16 bf16x8 __attribute__((ext_vector_type(8)));
typedef float  f32x4  __attribute__((ext_vector_type(4)));

#define GLOAD_LDS16(gptr, lptr)                                                     \
  __builtin_amdgcn_global_load_lds((__attribute__((address_space(1))) void*)(gptr), \
                                   (__attribute__((address_space(3))) void*)(lptr), \
                                   16, 0, 0)

template <int N> __device__ __forceinline__ void wait_vmcnt() {
  if constexpr (N == 0)      asm volatile("s_waitcnt vmcnt(0)" ::: "memory");
  else if constexpr (N == 3) asm volatile("s_waitcnt vmcnt(3)" ::: "memory");
  else if constexpr (N == 4) asm volatile("s_waitcnt vmcnt(4)" ::: "memory");
  else if constexpr (N == 6) asm volatile("s_waitcnt vmcnt(6)" ::: "memory");
  else static_assert(N == 0 || N == 3 || N == 4 || N == 6, "add vmcnt case");
}

// ---------------- merged convert kernel ----------------
__device__ __forceinline__ bf16x8 cvt8(const float* src) {
  const float4* s = (const float4*)src;
  float4 x = s[0], y = s[1];
  bf16x8 o;
  o[0] = (__bf16)x.x; o[1] = (__bf16)x.y; o[2] = (__bf16)x.z; o[3] = (__bf16)x.w;
  o[4] = (__bf16)y.x; o[5] = (__bf16)y.y; o[6] = (__bf16)y.z; o[7] = (__bf16)y.w;
  return o;
}

__global__ void cvt_all_k(const float* __restrict__ image, const float* __restrict__ Wcls,
                          const float* __restrict__ Wvis, const float* __restrict__ wemb,
                          const float* __restrict__ Wsem,
                          __bf16* __restrict__ imgB, __bf16* __restrict__ WcomB,
                          __bf16* __restrict__ wordB, __bf16* __restrict__ WsemB) {
  const int blk = blockIdx.x, tid = threadIdx.x;
  if (blk < 2048) {
    int i = blk * 256 + tid;
    ((bf16x8*)imgB)[i] = cvt8(image + (size_t)i * 8);
  } else if (blk < 4096) {
    int i = (blk - 2048) * 256 + tid;
    int row = i >> 8, cc = (i & 255) * 8;
    bf16x8 o;
    if (row < 1000)       o = cvt8(Wcls + (size_t)row * 2048 + cc);
    else if (row >= 1024) o = cvt8(Wvis + (size_t)(row - 1024) * 2048 + cc);
    else { for (int j = 0; j < 8; ++j) o[j] = (__bf16)0.f; }
    ((bf16x8*)WcomB)[i] = o;
  } else if (blk < 5376) {
    int i = (blk - 4096) * 256 + tid;
    int r = i / 320, c = i - r * 320;
    float v = (r < 1000 && c < 300) ? wemb[(size_t)r * 300 + c] : 0.f;
    wordB[i] = (__bf16)v;
  } else {
    int i = (blk - 5376) * 256 + tid;
    int r = i / 320, c = i - r * 320;
    float v = (c < 300) ? Wsem[(size_t)r * 300 + c] : 0.f;
    WsemB[i] = (__bf16)v;
  }
}

// ------- bf16 GEMM body, C = A @ B^T, BK=64, 3-buffer depth-2 counted pipeline -------
// LDS: At[3][BM*64] bf16 then Bt[3][BN*64] bf16 (16B chunk swizzle:
// logical chunk (r,c) of [rows][64]bf16 tile at slot r*8 + (c^(r&7));
// staging pre-swizzles the GLOBAL source, LDS dest stays linear).
// EPI 0: col<1000 -> outF=acc+bias1; col>=1024 -> outB=bf16(relu(acc+bias2)) at col-1024
// EPI 1: outB = bf16(relu(acc+bias1))
// EPI 2: col<1000 -> outF = acc
template <int WTM, int WTN, int NWM, int NWN, int EPI>
__device__ __forceinline__ void gemm_body(char* smem,
    const __bf16* __restrict__ A, const __bf16* __restrict__ Bm,
    const float* __restrict__ bias1, const float* __restrict__ bias2,
    float* __restrict__ outF, __bf16* __restrict__ outB, int K, int bm, int bn) {
  constexpr int BM = NWM * WTM, BN = NWN * WTN, NTHR = NWM * NWN * 64;
  constexpr int AM = WTM / 16, AN = WTN / 16;
  constexpr int LA = BM * 8 / NTHR, LB = BN * 8 / NTHR;   // 16B chunks per thread
  constexpr int LPS = LA + LB;
  char* AtB = smem;                        // 3 bufs x BM*128 bytes
  char* BtB = smem + 3 * BM * 128;         // 3 bufs x BN*128 bytes
  const int tid  = threadIdx.x;
  const int lane = tid & 63;
  const int wv   = tid >> 6;
  const int wvr  = wv / NWN, wvc = wv % NWN;

  f32x4 acc[AM][AN];
#pragma unroll
  for (int m = 0; m < AM; ++m)
#pragma unroll
    for (int n = 0; n < AN; ++n) acc[m][n] = (f32x4){0.f, 0.f, 0.f, 0.f};

  // kt-invariant swizzled read slots (bf16x8 index within a buffer)
  int slotA[2][AM], slotB[2][AN];
#pragma unroll
  for (int kh = 0; kh < 2; ++kh) {
#pragma unroll
    for (int m = 0; m < AM; ++m) {
      int r = wvr * WTM + m * 16 + (lane & 15);
      slotA[kh][m] = r * 8 + ((kh * 4 + (lane >> 4)) ^ (r & 7));
    }
#pragma unroll
    for (int n = 0; n < AN; ++n) {
      int r = wvc * WTN + n * 16 + (lane & 15);
      slotB[kh][n] = r * 8 + ((kh * 4 + (lane >> 4)) ^ (r & 7));
    }
  }

  const __bf16* Ab = A  + (size_t)(bm * BM) * K;
  const __bf16* Bb = Bm + (size_t)(bn * BN) * K;

#define STAGE64(buf, kt)                                                       \
  do {                                                                         \
    _Pragma("unroll")                                                          \
    for (int j = 0; j < LA; ++j) {                                             \
      int s = j * NTHR + tid;                                                  \
      int r = s >> 3, c = (s & 7) ^ (r & 7);                                   \
      GLOAD_LDS16(Ab + (size_t)r * K + (kt) * 64 + c * 8,                      \
                  AtB + (buf) * (BM * 128) + s * 16);                          \
    }                                                                          \
    _Pragma("unroll")                                                          \
    for (int j = 0; j < LB; ++j) {                                             \
      int s = j * NTHR + tid;                                                  \
      int r = s >> 3, c = (s & 7) ^ (r & 7);                                   \
      GLOAD_LDS16(Bb + (size_t)r * K + (kt) * 64 + c * 8,                      \
                  BtB + (buf) * (BN * 128) + s * 16);                          \
    }                                                                          \
  } while (0)

  const int nkt = K >> 6;      // >= 5 for all our shapes
  STAGE64(0, 0);
  STAGE64(1, 1);

  int cur = 0;
  for (int kt = 0; kt < nkt; ++kt) {
    // Outstanding: STAGE(kt) (+ STAGE(kt+1) if issued). Retire only STAGE(kt);
    // STAGE(kt+1)'s LPS loads keep flying across this barrier + compute phase.
    if (kt + 1 < nkt) wait_vmcnt<LPS>();
    else              wait_vmcnt<0>();
    __builtin_amdgcn_s_barrier();

    bf16x8 af[2][AM], bfr[2][AN];
    const bf16x8* Ap = (const bf16x8*)(AtB + cur * (BM * 128));
    const bf16x8* Bp = (const bf16x8*)(BtB + cur * (BN * 128));
#pragma unroll
    for (int kh = 0; kh < 2; ++kh) {
#pragma unroll
      for (int m = 0; m < AM; ++m) af[kh][m]  = Ap[slotA[kh][m]];
#pragma unroll
      for (int n = 0; n < AN; ++n) bfr[kh][n] = Bp[slotB[kh][n]];
    }
    __builtin_amdgcn_sched_barrier(0);   // ds_reads issued before STAGE

    if (kt + 2 < nkt) {
      int nb = cur + 2; if (nb >= 3) nb -= 3;
      STAGE64(nb, kt + 2);               // depth-2: flies across 2 phases
    }
    __builtin_amdgcn_sched_barrier(0);   // STAGE issued before MFMA cluster

#pragma unroll
    for (int kh = 0; kh < 2; ++kh)
#pragma unroll
      for (int m = 0; m < AM; ++m)
#pragma unroll
        for (int n = 0; n < AN; ++n)
          acc[m][n] = __builtin_amdgcn_mfma_f32_16x16x32_bf16(af[kh][m], bfr[kh][n],
                                                              acc[m][n], 0, 0, 0);
    ++cur; if (cur >= 3) cur = 0;
  }
#undef STAGE64

  // epilogue: C/D layout col=lane&15, row=(lane>>4)*4+j (m89/m91-verified)
#pragma unroll
  for (int m = 0; m < AM; ++m) {
    const int row0 = bm * BM + wvr * WTM + m * 16 + ((lane >> 4) << 2);
#pragma unroll
    for (int n = 0; n < AN; ++n) {
      const int col = bn * BN + wvc * WTN + n * 16 + (lane & 15);
      if (EPI == 0) {
        if (col < 1000) {
          const float bz = bias1[col];
#pragma unroll
          for (int j = 0; j < 4; ++j)
            outF[(size_t)(row0 + j) * 1000 + col] = acc[m][n][j] + bz;
        } else if (col >= 1024) {
          const float bz = bias2[col - 1024];
#pragma unroll
          for (int j = 0; j < 4; ++j) {
            float v = acc[m][n][j] + bz;
            outB[(size_t)(row0 + j) * 1024 + (col - 1024)] = (__bf16)fmaxf(v, 0.f);
          }
        }
      } else if (EPI == 1) {
        const float bz = bias1[col];
#pragma unroll
        for (int j = 0; j < 4; ++j) {
          float v = acc[m][n][j] + bz;
          outB[(size_t)(row0 + j) * 1024 + col] = (__bf16)fmaxf(v, 0.f);
        }
      } else {
        if (col < 1000) {
#pragma unroll
          for (int j = 0; j < 4; ++j)
            outF[(size_t)(row0 + j) * 1000 + col] = acc[m][n][j];
        }
      }
    }
  }
}

// Blocks 0-255: fused logits+V GEMM (128x128 tiles, 8 waves of 32x64).
// Blocks 256-383: S GEMM (64x128 tiles, 8 waves of 32x32) — tail-fill.
__global__ void __launch_bounds__(512, 2)
gemm_merged_k(const __bf16* __restrict__ imgB, const __bf16* __restrict__ WcomB,
              const __bf16* __restrict__ wordB, const __bf16* __restrict__ WsemB,
              const float* __restrict__ bcls, const float* __restrict__ bvis,
              const float* __restrict__ bsem,
              float* __restrict__ logits, __bf16* __restrict__ Vb,
              __bf16* __restrict__ Sb) {
  extern __shared__ char smem[];
  const int blk = blockIdx.x;
  if (blk < 256) {
    gemm_body<32, 64, 4, 2, 0>(smem, imgB, WcomB, bcls, bvis, logits, Vb, 2048,
                               blk >> 4, blk & 15);
  } else {
    const int l = blk - 256;                 // 0..127: S is [1024][1024]
    gemm_body<32, 32, 2, 4, 1>(smem, wordB, WsemB, bsem, nullptr, nullptr, Sb, 320,
                               l >> 3, l & 7);
  }
}

// scores: 64x64 blocks (4 waves 32x32), grid 16x32 = 512 blocks. [R9 exact]
__global__ void __launch_bounds__(256, 2)
gemm_scores_k(const __bf16* __restrict__ Vb, const __bf16* __restrict__ Sb,
              float* __restrict__ scores) {
  extern __shared__ char smem[];
  gemm_body<32, 32, 2, 2, 2>(smem, Vb, Sb, nullptr, nullptr, scores, nullptr, 1024,
                             blockIdx.y, blockIdx.x);
}

// ---------------- launch ----------------

extern "C" void kernel_launch(void* const* d_in, const int* in_sizes, int n_in,
                              void* d_out, int out_size, void* d_ws, size_t ws_size,
                              hipStream_t stream) {
  const float* image = (const float*)d_in[0];
  const float* wemb  = (const float*)d_in[1];
  const float* Wcls  = (const float*)d_in[2];
  const float* bcls  = (const float*)d_in[3];
  const float* Wvis  = (const float*)d_in[4];
  const float* bvis  = (const float*)d_in[5];
  const float* Wsem  = (const float*)d_in[6];
  const float* bsem  = (const float*)d_in[7];

  float* logits = (float*)d_out;                  // [2048][1000]
  float* scores = logits + (size_t)2048 * 1000;   // [2048][1000]

  char* ws = (char*)d_ws;
  __bf16* imgB  = (__bf16*)(ws);
  __bf16* WcomB = (__bf16*)(ws + 8388608);
  __bf16* Vb    = (__bf16*)(ws + 16777216);
  __bf16* Sb    = (__bf16*)(ws + 20971520);
  __bf16* wordB = (__bf16*)(ws + 23068672);
  __bf16* WsemB = (__bf16*)(ws + 23724032);

  cvt_all_k<<<6656, 256, 0, stream>>>(image, Wcls, Wvis, wemb, Wsem,
                                      imgB, WcomB, wordB, WsemB);

  // fused (256 blocks, 128x128, K=2048) + S (128 blocks, 64x128, K=320)
  // dynamic LDS = 3*(128+128)*128 = 98304 B -> 1 block/CU, 8 waves (2/SIMD)
  gemm_merged_k<<<384, 512, 98304, stream>>>(imgB, WcomB, wordB, WsemB,
                                             bcls, bvis, bsem, logits, Vb, Sb);

  // scores: [2048 x 1024pad] = Vb @ Sb^T, K=1024, 64x64 tiles, grid (16,32)
  // dynamic LDS = 3*(64+64)*128 = 49152 B -> 3 blocks/CU
  gemm_scores_k<<<dim3(16, 32), 256, 49152, stream>>>(Vb, Sb, scores);
}